// Round 2
// baseline (259.268 us; speedup 1.0000x reference)
//
#include <hip/hip_runtime.h>
#include <math.h>

#define NPIX 65536
#define NB   4
#define NK   6
#define TK   8
#define NBUK 48   // NK*TK
#define NCH  256
#define GSP  2    // plane split in k_accum
#define NSEL (NB*NK*TK)   // 192 simultaneous selections

// ---------------- init: zero atomic targets + histograms ----------------
__global__ __launch_bounds__(256) void k_init(unsigned* m_arr, unsigned* Mbits,
                                              unsigned* hist0, unsigned* hist8) {
  int i = blockIdx.x * 256 + threadIdx.x;     // grid 64 -> 16384 threads
  if (i < NB * NK) { m_arr[i] = 0u; Mbits[i] = 0u; }
  for (int j = i; j < NSEL / TK * 256; j += 256 * 64) hist0[j] = 0u;   // 6144
  for (int j = i; j < NSEL * 256; j += 256 * 64) hist8[j] = 0u;        // 49152
}

// ---------------- A1: cert, argmax, per-class m/M, pass-0 radix histogram ----------------
__global__ __launch_bounds__(256) void k_cert(const float* __restrict__ preds,
    float* __restrict__ cert, unsigned char* __restrict__ argm,
    unsigned* __restrict__ m_arr, unsigned* __restrict__ Mbits,
    unsigned* __restrict__ hist0) {
  __shared__ unsigned s_cnt[NK], s_max[NK];
  __shared__ unsigned s_hist[NK * 256];
  int tid = threadIdx.x;
  if (tid < NK) { s_cnt[tid] = 0u; s_max[tid] = 0u; }
  for (int j = tid; j < NK * 256; j += 256) s_hist[j] = 0u;
  __syncthreads();
  int i = blockIdx.x * 256 + tid;            // 4 pixels each
  int n4 = i << 2;
  int b = n4 >> 16;
  int n = n4 & (NPIX - 1);
  const float* pb = preds + (size_t)b * NK * NPIX + n;
  float4 pv[NK];
  #pragma unroll
  for (int k = 0; k < NK; ++k) pv[k] = *(const float4*)(pb + (size_t)k * NPIX);
  float cv[4]; unsigned av = 0;
  #pragma unroll
  for (int j = 0; j < 4; ++j) {
    float m1 = -INFINITY, m2 = -INFINITY; int arg = 0;
    #pragma unroll
    for (int k = 0; k < NK; ++k) {
      float v = (j == 0) ? pv[k].x : (j == 1) ? pv[k].y : (j == 2) ? pv[k].z : pv[k].w;
      if (v > m1) { m2 = m1; m1 = v; arg = k; }
      else if (v > m2) m2 = v;
    }
    float c = m1 - m2;                        // >= 0
    cv[j] = c;
    av |= ((unsigned)arg) << (8 * j);
    unsigned u = __float_as_uint(c);
    atomicAdd(&s_cnt[arg], 1u);
    atomicMax(&s_max[arg], u);
    atomicAdd(&s_hist[arg * 256 + (u >> 24)], 1u);
  }
  *(float4*)(cert + (size_t)b * NPIX + n) = make_float4(cv[0], cv[1], cv[2], cv[3]);
  *(unsigned*)(argm + (size_t)b * NPIX + n) = av;
  __syncthreads();
  if (tid < NK) {
    if (s_cnt[tid]) atomicAdd(&m_arr[b * NK + tid], s_cnt[tid]);
    atomicMax(&Mbits[b * NK + tid], s_max[tid]);
  }
  for (int j = tid; j < NK * 256; j += 256)
    if (s_hist[j]) atomicAdd(&hist0[b * NK * 256 + j], s_hist[j]);
}

// ---------------- radix scan pass p (p=1,2,3): histogram next 8 bits for matching prefixes ----
__global__ __launch_bounds__(256) void k_scan(const float* __restrict__ cert,
    const unsigned char* __restrict__ argm, const unsigned* __restrict__ pref,
    const unsigned* __restrict__ rank, unsigned* __restrict__ hist8, int pass) {
  __shared__ unsigned s_pref[NSEL], s_rank[NSEL];
  int tid = threadIdx.x;
  if (tid < NSEL) { s_pref[tid] = pref[tid]; s_rank[tid] = rank[tid]; }
  __syncthreads();
  int ps = 32 - 8 * pass;                    // prefix compare shift
  int bs = 24 - 8 * pass;                    // bin shift
  int b = blockIdx.x >> 6;                   // 4 batches x 64 segments
  int seg = blockIdx.x & 63;
  int n = seg * 1024 + tid * 4;
  float4 cv = *(const float4*)(cert + (size_t)b * NPIX + n);
  unsigned av = *(const unsigned*)(argm + (size_t)b * NPIX + n);
  #pragma unroll
  for (int j = 0; j < 4; ++j) {
    int c = (av >> (8 * j)) & 255;
    unsigned u = __float_as_uint((j == 0) ? cv.x : (j == 1) ? cv.y : (j == 2) ? cv.z : cv.w);
    unsigned top = u >> ps;
    int base = (b * NK + c) * TK;
    #pragma unroll
    for (int r = 0; r < TK; ++r) {
      int idx = base + r;
      if (s_rank[idx] && top == s_pref[idx])
        atomicAdd(&hist8[idx * 256 + ((u >> bs) & 255u)], 1u);
    }
  }
}

// ---------------- combine pass p: walk histograms downward, refine prefix+rank ----------------
__global__ __launch_bounds__(256) void k_combine(const unsigned* __restrict__ hist0,
    unsigned* __restrict__ hist8, const unsigned* __restrict__ m_arr,
    unsigned* __restrict__ pref, unsigned* __restrict__ rank,
    float* __restrict__ thr, int pass) {
  int t = threadIdx.x;
  if (t < NSEL) {
    if (pass == 0) {
      int bc = t >> 3, r = t & 7;
      unsigned m = m_arr[bc];
      unsigned rk = 0;
      if (m) {
        unsigned long long ks = ((unsigned long long)m * (unsigned)(r + 1)) / TK;
        rk = ks ? (unsigned)ks : 1u;
      }
      pref[t] = 0u; rank[t] = 0u;
      if (rk) {
        const unsigned* h = hist0 + bc * 256;
        unsigned cum = 0;
        for (int bin = 255; bin >= 0; --bin) {
          unsigned hh = h[bin]; cum += hh;
          if (cum >= rk) { pref[t] = (unsigned)bin; rank[t] = rk - (cum - hh); break; }
        }
      }
    } else {
      unsigned rk = rank[t];
      if (rk) {
        const unsigned* h = hist8 + t * 256;
        unsigned cum = 0;
        for (int bin = 255; bin >= 0; --bin) {
          unsigned hh = h[bin]; cum += hh;
          if (cum >= rk) { pref[t] = (pref[t] << 8) | (unsigned)bin; rank[t] = rk - (cum - hh); break; }
        }
      }
      if (pass == 3) thr[t] = rk ? __uint_as_float(pref[t]) : 0.f;
    }
  }
  if (pass == 1 || pass == 2) {               // zero hist8 for next pass
    __syncthreads();
    for (int i = t; i < NSEL * 256; i += 256) hist8[i] = 0u;
  }
}

// ---------------- A3: per-pixel packed (e | bucket) ----------------
__global__ __launch_bounds__(256) void k_bucket(const float* __restrict__ cert,
    const unsigned char* __restrict__ argm, const unsigned* __restrict__ Mbits,
    const float* __restrict__ thr, unsigned* __restrict__ eb_out) {
  __shared__ float s_thr[NSEL];
  __shared__ float s_M[NB * NK];
  int tid = threadIdx.x;
  if (tid < NSEL) s_thr[tid] = thr[tid];
  if (tid < NB * NK) s_M[tid] = __uint_as_float(Mbits[tid]);
  __syncthreads();
  int i = blockIdx.x * 256 + tid;
  int n4 = i << 2;
  int b = n4 >> 16;
  int n = n4 & (NPIX - 1);
  float4 cv = *(const float4*)(cert + (size_t)b * NPIX + n);
  unsigned av = *(const unsigned*)(argm + (size_t)b * NPIX + n);
  uint4 ev;
  unsigned evv[4];
  #pragma unroll
  for (int j = 0; j < 4; ++j) {
    int c = (av >> (8 * j)) & 255;
    float ce = (j == 0) ? cv.x : (j == 1) ? cv.y : (j == 2) ? cv.z : cv.w;
    float e = expf(ce - s_M[b * NK + c]);
    const float* tc = &s_thr[(b * NK + c) * TK];
    int tmin = TK - 1;
    #pragma unroll
    for (int tt = TK - 2; tt >= 0; --tt) if (ce >= tc[tt]) tmin = tt;
    evv[j] = (__float_as_uint(e) & 0xFFFFFFC0u) | (unsigned)(c * TK + tmin);
  }
  ev.x = evv[0]; ev.y = evv[1]; ev.z = evv[2]; ev.w = evv[3];
  *(uint4*)(eb_out + (size_t)b * NPIX + n) = ev;
}

// ---------------- B: pipelined single pass over x, lane-owned LDS buckets ----------------
// grid = NB*(NCH+1)*GSP; chz==NCH is the z-plane (x==1) for deterministic Z sums.
#define PROC(ev, xv) do { \
    unsigned u_; \
    u_ = ev.x; mycol[(u_ & 63u) * 64] += xv.x * __uint_as_float(u_ & 0xFFFFFFC0u); \
    u_ = ev.y; mycol[(u_ & 63u) * 64] += xv.y * __uint_as_float(u_ & 0xFFFFFFC0u); \
    u_ = ev.z; mycol[(u_ & 63u) * 64] += xv.z * __uint_as_float(u_ & 0xFFFFFFC0u); \
    u_ = ev.w; mycol[(u_ & 63u) * 64] += xv.w * __uint_as_float(u_ & 0xFFFFFFC0u); \
  } while (0)

__global__ __launch_bounds__(256) void k_accum(const float* __restrict__ x,
    const unsigned* __restrict__ eb, float* __restrict__ psum, float* __restrict__ zbuf) {
  __shared__ float acc[4 * NBUK * 64];        // [wave][bucket][lane] -> bank = lane%32, free
  __shared__ float wpart[4 * NBUK];
  int tid = threadIdx.x;
  int w = tid >> 6, lane = tid & 63;
  float* mycol = acc + (size_t)w * NBUK * 64 + lane;
  #pragma unroll
  for (int k = 0; k < NBUK; ++k) mycol[k * 64] = 0.f;
  __syncthreads();
  int blk = blockIdx.x;
  int g = blk & (GSP - 1);
  int pc = blk / GSP;
  int b = pc / (NCH + 1);
  int chz = pc % (NCH + 1);
  bool isz = (chz == NCH);
  const unsigned* ep = eb + (size_t)b * NPIX + g * (NPIX / GSP);
  const float* xp = x + ((size_t)b * NCH + chz) * NPIX + g * (NPIX / GSP);
  const int NIT = NPIX / GSP / 1024;          // 32
  int o = tid * 4;
  // prologue: load iterations 0,1
  uint4 e0 = *(const uint4*)(ep + o);
  uint4 e1 = *(const uint4*)(ep + o + 1024);
  float4 x0 = make_float4(1.f, 1.f, 1.f, 1.f), x1 = x0;
  if (!isz) { x0 = *(const float4*)(xp + o); x1 = *(const float4*)(xp + o + 1024); }
  for (int it = 0; it < NIT; it += 2) {
    uint4 e2, e3; float4 x2, x3;
    bool more = (it + 2 < NIT);
    if (more) {                               // prefetch 2 iterations ahead
      e2 = *(const uint4*)(ep + o + (it + 2) * 1024);
      e3 = *(const uint4*)(ep + o + (it + 3) * 1024);
      if (!isz) {
        x2 = *(const float4*)(xp + o + (it + 2) * 1024);
        x3 = *(const float4*)(xp + o + (it + 3) * 1024);
      } else { x2 = make_float4(1.f, 1.f, 1.f, 1.f); x3 = x2; }
    }
    PROC(e0, x0);
    PROC(e1, x1);
    if (more) { e0 = e2; x0 = x2; e1 = e3; x1 = x3; }
  }
  __syncthreads();
  for (int k = 0; k < NBUK; ++k) {
    float v = mycol[k * 64];
    #pragma unroll
    for (int d = 1; d < 64; d <<= 1) v += __shfl_xor(v, d, 64);
    if (lane == 0) wpart[w * NBUK + k] = v;
  }
  __syncthreads();
  if (tid < NBUK) {
    float s = wpart[tid] + wpart[NBUK + tid] + wpart[2 * NBUK + tid] + wpart[3 * NBUK + tid];
    if (!isz) psum[((size_t)g * NB * NCH + (size_t)b * NCH + chz) * NBUK + tid] = s;
    else      zbuf[((size_t)g * NB + b) * NBUK + tid] = s;
  }
}

// ---------------- F: prefix over t, branch on m, write fs + fg ----------------
__global__ __launch_bounds__(256) void k_final(const float* __restrict__ psum,
    const float* __restrict__ zbuf, const unsigned* __restrict__ m_arr,
    float* __restrict__ out) {
  int i = blockIdx.x * 256 + threadIdx.x;     // (b, ch)
  if (i >= NB * NCH) return;
  int b = i >> 8;
  const float* ps0 = psum + (size_t)i * NBUK;
  const float* ps1 = psum + (size_t)NB * NCH * NBUK + (size_t)i * NBUK;
  const float* zb0 = zbuf + (size_t)b * NBUK;
  const float* zb1 = zbuf + (size_t)NB * NBUK + (size_t)b * NBUK;
  float* fs = out + (size_t)i * NBUK;
  float* fg = out + (size_t)NB * NCH * NBUK + (size_t)i * NK;
  float t5[TK];
  #pragma unroll
  for (int c = 0; c < NK; ++c) {
    unsigned m = m_arr[b * NK + c];
    float P = 0.f, Z = 0.f;
    float vals[TK];
    #pragma unroll
    for (int t = 0; t < TK; ++t) {
      P += ps0[c * TK + t] + ps1[c * TK + t];
      Z += zb0[c * TK + t] + zb1[c * TK + t];
      vals[t] = P / Z;
    }
    float tot = vals[TK - 1];
    #pragma unroll
    for (int t = 0; t < TK; ++t) {
      float v = (m == 0u) ? 0.f : ((m < (unsigned)TK) ? tot : vals[t]);
      fs[c * TK + t] = v;
      if (c == NK - 1) t5[t] = v;
    }
  }
  #pragma unroll
  for (int v = 0; v < NK; ++v) fg[v] = t5[2 + v];
}

extern "C" void kernel_launch(void* const* d_in, const int* in_sizes, int n_in,
                              void* d_out, int out_size, void* d_ws, size_t ws_size,
                              hipStream_t stream) {
  const float* x     = (const float*)d_in[0];   // [4,256,256,256]
  const float* preds = (const float*)d_in[1];   // [4,6,256,256]
  float* out = (float*)d_out;
  char* ws = (char*)d_ws;
  float*         cert  = (float*)(ws);                       // 1 MiB
  unsigned char* argm  = (unsigned char*)(ws + 0x100000);    // 256 KiB
  unsigned*      eb    = (unsigned*)(ws + 0x140000);         // 1 MiB
  unsigned*      m_arr = (unsigned*)(ws + 0x240000);         // 24 u32
  unsigned*      Mbits = (unsigned*)(ws + 0x240100);         // 24 u32
  unsigned*      pref  = (unsigned*)(ws + 0x240200);         // 192 u32
  unsigned*      rank  = (unsigned*)(ws + 0x240600);         // 192 u32
  float*         thr   = (float*)(ws + 0x240A00);            // 192 f32
  unsigned*      hist0 = (unsigned*)(ws + 0x241000);         // 24 KiB
  unsigned*      hist8 = (unsigned*)(ws + 0x248000);         // 192 KiB
  float*         psum  = (float*)(ws + 0x280000);            // 384 KiB
  float*         zbuf  = (float*)(ws + 0x2E0000);            // 1.5 KiB

  k_init   <<<64, 256, 0, stream>>>(m_arr, Mbits, hist0, hist8);
  k_cert   <<<256, 256, 0, stream>>>(preds, cert, argm, m_arr, Mbits, hist0);
  k_combine<<<1, 256, 0, stream>>>(hist0, hist8, m_arr, pref, rank, thr, 0);
  k_scan   <<<256, 256, 0, stream>>>(cert, argm, pref, rank, hist8, 1);
  k_combine<<<1, 256, 0, stream>>>(hist0, hist8, m_arr, pref, rank, thr, 1);
  k_scan   <<<256, 256, 0, stream>>>(cert, argm, pref, rank, hist8, 2);
  k_combine<<<1, 256, 0, stream>>>(hist0, hist8, m_arr, pref, rank, thr, 2);
  k_scan   <<<256, 256, 0, stream>>>(cert, argm, pref, rank, hist8, 3);
  k_combine<<<1, 256, 0, stream>>>(hist0, hist8, m_arr, pref, rank, thr, 3);
  k_bucket <<<256, 256, 0, stream>>>(cert, argm, Mbits, thr, eb);
  k_accum  <<<NB * (NCH + 1) * GSP, 256, 0, stream>>>(x, eb, psum, zbuf);
  k_final  <<<4, 256, 0, stream>>>(psum, zbuf, m_arr, out);
}